// Round 16
// baseline (639.973 us; speedup 1.0000x reference)
//
#include <hip/hip_runtime.h>

#define NB 1024
#define NT 16
#define NIM 11
#define PIT 20
#define NTH 128   // one filter per 128-thread block

struct __align__(16) SharedBlob {
    float P0[19*PIT];
    float P1[19*PIT];
    float A9[9*PIT];        // A = (Phi P) rows 3..11
    float Dall[10][9*PIT];  // Delta rows 3..11 per substep (static zeros elsewhere)
    float Wsall[10][9*12];  // W * sqrt(Rd) per substep
    float Wu[19*12];        // PHt (cols 0..5) then KH (cols 0..6)
    float Mu[19*12];        // K
    float Rd[12];
    float sqRd[12];
    float Aug[2][84];
    float E[20];
    float dts[12];          // dt per substep
    unsigned short tri[192];
};

__device__ __forceinline__ float sel3(int i, float a, float b, float c){
    return i==0 ? a : (i==1 ? b : c);
}
__device__ __forceinline__ void skew3(float x, float y, float z, float K[9]) {
    K[0]=0.f;  K[1]=-z;   K[2]=y;
    K[3]=z;    K[4]=0.f;  K[5]=-x;
    K[6]=-y;   K[7]=x;    K[8]=0.f;
}
__device__ __forceinline__ void mm3(const float A[9], const float Bm[9], float C[9]) {
#pragma unroll
    for (int i=0;i<3;i++)
#pragma unroll
        for (int j=0;j<3;j++)
            C[i*3+j] = A[i*3+0]*Bm[0+j] + A[i*3+1]*Bm[3+j] + A[i*3+2]*Bm[6+j];
}
__device__ __forceinline__ void exp_SO3f(float p0, float p1, float p2, float R[9]) {
    float t2 = p0*p0+p1*p1+p2*p2;
    bool sm = t2 < 1e-8f;
    float t2s = sm ? 1.0f : t2;
    float t = sqrtf(t2s);
    float sn, cs; __sincosf(t, &sn, &cs);
    float A = sm ? (1.0f - t2*(1.0f/6.0f)) : (sn/t);
    float Bc = sm ? (0.5f - t2*(1.0f/24.0f)) : ((1.0f - cs)/t2s);
    float K[9]; skew3(p0,p1,p2,K);
    float K2[9]; mm3(K,K,K2);
#pragma unroll
    for (int i=0;i<9;i++) R[i] = A*K[i] + Bc*K2[i];
    R[0]+=1.f; R[4]+=1.f; R[8]+=1.f;
}
__device__ __forceinline__ void log_SO3(const float C[9], float p[3]) {
    float tr = C[0]+C[4]+C[8];
    float c = (tr-1.0f)*0.5f;
    c = fminf(fmaxf(c, -1.0f+1e-7f), 1.0f-1e-7f);
    float t = acosf(c);
    bool sm = t < 1e-4f;
    float s = sm ? 1.0f : sinf(t);
    float coef = sm ? (0.5f + t*t*(1.0f/12.0f)) : (t/(2.0f*s));
    p[0] = coef*(C[7]-C[5]);
    p[1] = coef*(C[2]-C[6]);
    p[2] = coef*(C[3]-C[1]);
}
__device__ __forceinline__ void J_left_inv(const float p[3], float J[9]) {
    float t2 = p[0]*p[0]+p[1]*p[1]+p[2]*p[2];
    bool sm = t2 < 1e-8f;
    float t2s = sm ? 1.0f : t2;
    float t = sqrtf(t2s);
    float coef = sm ? (1.0f/12.0f) : (1.0f/t2s - (1.0f+cosf(t))/(2.0f*t*sinf(t)));
    float K[9]; skew3(p[0],p[1],p[2],K);
    float K2[9]; mm3(K,K,K2);
#pragma unroll
    for (int i=0;i<9;i++) J[i] = -0.5f*K[i] + coef*K2[i];
    J[0]+=1.f; J[4]+=1.f; J[8]+=1.f;
}
__device__ __forceinline__ float dot12_rr(const float* a, const float* b){
    const float4* a4=(const float4*)a;
    const float4* b4=(const float4*)b;
    float s=0.f;
#pragma unroll
    for (int q=0;q<3;q++){
        float4 x=a4[q], y=b4[q];
        s += x.x*y.x + x.y*y.y + x.z*y.z + x.w*y.w;
    }
    return s;
}
// D-row sparse dot: jb = (row block of D), exploits static zero pattern
__device__ __forceinline__ float dotD(const float* Ai, const float* Dr, int jb){
    float s = Ai[3]*Dr[3]+Ai[4]*Dr[4]+Ai[5]*Dr[5];
    if (jb==0){
        s += Ai[12]*Dr[12]+Ai[13]*Dr[13]+Ai[14]*Dr[14];
    } else {
        s += Ai[0]*Dr[0]+Ai[1]*Dr[1]+Ai[2]*Dr[2]
           + Ai[9]*Dr[9]+Ai[10]*Dr[10]+Ai[11]*Dr[11]
           + Ai[15]*Dr[15]+Ai[16]*Dr[16]+Ai[17]*Dr[17];
        if (jb==2) s += Ai[12]*Dr[12]+Ai[13]*Dr[13]+Ai[14]*Dr[14];
    }
    return s;
}

__global__ void __launch_bounds__(NTH, 2) kf_kernel(
    const float* __restrict__ imu_data,
    const float* __restrict__ Rimu,
    const float* __restrict__ prev_pose,
    const float* __restrict__ prev_state,
    const float* __restrict__ prev_covar,
    const float* __restrict__ vis_meas,
    const float* __restrict__ vis_covar,
    float* __restrict__ out_poses,
    float* __restrict__ out_states,
    float* __restrict__ out_covars)
{
    __shared__ SharedBlob S;
    const int t = threadIdx.x;         // thread within filter
    const int b = blockIdx.x;          // batch element
    const int w = t >> 6;              // wave (0/1)
    const int l = t & 63;              // lane within wave

    // ---- init ----
    const float* pcv = prev_covar + (size_t)b*361;
    for (int e=t;e<361;e+=NTH){
        float v = pcv[e];
        int i=e/19, j=e%19;
        bool msk = (i>=3&&i<9)||(j>=3&&j<9);
        S.P0[i*PIT + j] = msk ? 0.f : v;      // masked for first predict
        out_covars[((size_t)b*17)*361 + e] = v;
    }
    for (int e=t;e<10*9*PIT;e+=NTH) S.Dall[0][e] = 0.f;   // static zero pattern
    if (t<12){ float rv = Rimu[t*12+t]; S.Rd[t]=rv; S.sqRd[t]=sqrtf(rv); }
    if (t<16) out_poses[((size_t)b*17)*16 + t] = prev_pose[(size_t)b*16+t];
    if (t<25) out_states[((size_t)b*17)*25 + t] = prev_state[(size_t)b*25+t];
    for (int e=t;e<190;e+=NTH){
        int i=0, rem=e;
        while (rem >= 19-i){ rem -= 19-i; i++; }
        S.tri[e] = (unsigned short)((i<<5)|(i+rem));
    }

    const float* st = prev_state + (size_t)b*25;
    float g0=st[0], g1=st[1], g2=st[2];
    float vk0=st[15], vk1=st[16], vk2=st[17];
    float bw0=st[18], bw1=st[19], bw2=st[20];
    float ba0=st[21], ba1=st[22], ba2=st[23];
    float lam=st[24];
    const float* pp = prev_pose + (size_t)b*16;
    float pR[9] = {pp[0],pp[1],pp[2], pp[4],pp[5],pp[6], pp[8],pp[9],pp[10]};
    float pT0=pp[3], pT1=pp[7], pT2=pp[11];

    __syncthreads();

    for (int k=0;k<NT;k++){
        // =========== PREDICT: precompute phase (no block barriers) ===========
        float Cc[9] = {1,0,0, 0,1,0, 0,0,1};
        float ra0=0,ra1=0,ra2=0, va0=0,va1=0,va2=0, tac=0;
        const float* imu = imu_data + ((size_t)b*NT + k)*NIM*7;

        for (int s=0;s<NIM-1;s++){
            const float* m0 = imu + s*7;
            float dt = m0[7] - m0[0];
            float w0=m0[1]-bw0, w1=m0[2]-bw1, w2=m0[3]-bw2;
            float a0=m0[4]-ba0, a1=m0[5]-ba1, a2=m0[6]-ba2;
            float u0=vk0-g0*tac+va0, u1=vk1-g1*tac+va1, u2=vk2-g2*tac+va2;
            float vv0=Cc[0]*u0+Cc[3]*u1+Cc[6]*u2;
            float vv1=Cc[1]*u0+Cc[4]*u1+Cc[7]*u2;
            float vv2=Cc[2]*u0+Cc[5]*u1+Cc[8]*u2;
            float ct0=Cc[0]*g0+Cc[3]*g1+Cc[6]*g2;
            float ct1=Cc[1]*g0+Cc[4]*g1+Cc[7]*g2;
            float ct2=Cc[2]*g0+Cc[5]*g1+Cc[8]*g2;
            float Em[9]; exp_SO3f(dt*w0, dt*w1, dt*w2, Em);
            float hdt2 = 0.5f*dt*dt;

            // wave0 lanes 0..26 write Delta(s) entries (disjoint per-substep buffers)
            if (t<27){
                int r=t/9, ii=(t%9)/3, jj=t%3;
                float dij = (ii==jj)?1.f:0.f;
                int o = ii*PIT + jj;
                float* Dp = S.Dall[s];
                if (r==0){
                    float eJ0=sel3(jj,Em[0],Em[3],Em[6]), eJ1=sel3(jj,Em[1],Em[4],Em[7]), eJ2=sel3(jj,Em[2],Em[5],Em[8]);
                    float EmTIJ = sel3(ii,eJ0,eJ1,eJ2);
                    float wcJ0=sel3(jj,0.f,-w2,w1), wcJ1=sel3(jj,w2,0.f,-w0), wcJ2=sel3(jj,-w1,w0,0.f);
                    float wskIJ = sel3(ii,wcJ0,wcJ1,wcJ2);
                    Dp[o+3]  = EmTIJ - dij;
                    Dp[o+12] = -dt*dij + hdt2*wskIJ;
                } else if (r==1){
                    float cI0=sel3(ii,Cc[0],Cc[3],Cc[6]), cI1=sel3(ii,Cc[1],Cc[4],Cc[7]), cI2=sel3(ii,Cc[2],Cc[5],Cc[8]);
                    float cJ0=sel3(jj,Cc[0],Cc[3],Cc[6]), cJ1=sel3(jj,Cc[1],Cc[4],Cc[7]), cJ2=sel3(jj,Cc[2],Cc[5],Cc[8]);
                    float ccJ0=sel3(jj,Cc[0],Cc[1],Cc[2]), ccJ1=sel3(jj,Cc[3],Cc[4],Cc[5]), ccJ2=sel3(jj,Cc[6],Cc[7],Cc[8]);
                    float CIJ = sel3(ii,ccJ0,ccJ1,ccJ2);
                    float vcJ0=sel3(jj,0.f,-vv2,vv1), vcJ1=sel3(jj,vv2,0.f,-vv0), vcJ2=sel3(jj,-vv1,vv0,0.f);
                    float tcJ0=sel3(jj,0.f,-ct2,ct1), tcJ1=sel3(jj,ct2,0.f,-ct0), tcJ2=sel3(jj,-ct1,ct0,0.f);
                    float wcJ0=sel3(jj,0.f,-w2,w1), wcJ1=sel3(jj,w2,0.f,-w0), wcJ2=sel3(jj,-w1,w0,0.f);
                    float CCtIJ  = cI0*cJ0 + cI1*cJ1 + cI2*cJ2;
                    float CvskIJ = cI0*vcJ0 + cI1*vcJ1 + cI2*vcJ2;
                    float Cv0 =  cI1*vv2 - cI2*vv1;
                    float Cv1 = -cI0*vv2 + cI2*vv0;
                    float Cv2 =  cI0*vv1 - cI1*vv0;
                    float CvwIJ = Cv0*wcJ0 + Cv1*wcJ1 + Cv2*wcJ2;
                    float CctIJ = cI0*tcJ0 + cI1*tcJ1 + cI2*tcJ2;
                    float CwIJ  = cI0*wcJ0 + cI1*wcJ1 + cI2*wcJ2;
                    Dp[3*PIT + o + 0]  = -hdt2*CCtIJ;
                    Dp[3*PIT + o + 3]  = -dt*CvskIJ + hdt2*(CvwIJ - CctIJ);
                    Dp[3*PIT + o + 9]  =  dt*CIJ - hdt2*CwIJ;
                    Dp[3*PIT + o + 15] = -hdt2*CIJ;
                } else {
                    float cJ0=sel3(jj,Cc[0],Cc[3],Cc[6]), cJ1=sel3(jj,Cc[1],Cc[4],Cc[7]), cJ2=sel3(jj,Cc[2],Cc[5],Cc[8]);
                    float CTIJ = sel3(ii,cJ0,cJ1,cJ2);
                    float eJ0=sel3(jj,Em[0],Em[3],Em[6]), eJ1=sel3(jj,Em[1],Em[4],Em[7]), eJ2=sel3(jj,Em[2],Em[5],Em[8]);
                    float EmTIJ = sel3(ii,eJ0,eJ1,eJ2);
                    float wrI0=sel3(ii,0.f,w2,-w1), wrI1=sel3(ii,-w2,0.f,w0), wrI2=sel3(ii,w1,-w0,0.f);
                    float wcJ0=sel3(jj,0.f,-w2,w1), wcJ1=sel3(jj,w2,0.f,-w0), wcJ2=sel3(jj,-w1,w0,0.f);
                    float wskIJ = sel3(ii,wcJ0,wcJ1,wcJ2);
                    float vcJ0=sel3(jj,0.f,-vv2,vv1), vcJ1=sel3(jj,vv2,0.f,-vv0), vcJ2=sel3(jj,-vv1,vv0,0.f);
                    float vskIJ = sel3(ii,vcJ0,vcJ1,vcJ2);
                    float trI0=sel3(ii,0.f,ct2,-ct1), trI1=sel3(ii,-ct2,0.f,ct0), trI2=sel3(ii,ct1,-ct0,0.f);
                    float tcJ0=sel3(jj,0.f,-ct2,ct1), tcJ1=sel3(jj,ct2,0.f,-ct0), tcJ2=sel3(jj,-ct1,ct0,0.f);
                    float ctskIJ = sel3(ii,tcJ0,tcJ1,tcJ2);
                    float wCtIJ = wrI0*cJ0 + wrI1*cJ1 + wrI2*cJ2;
                    float ctwIJ = trI0*wcJ0 + trI1*wcJ1 + trI2*wcJ2;
                    float wctIJ = wrI0*tcJ0 + wrI1*tcJ1 + wrI2*tcJ2;
                    float wvIJ  = wrI0*vcJ0 + wrI1*vcJ1 + wrI2*vcJ2;
                    Dp[6*PIT + o + 0]  = -dt*CTIJ + hdt2*wCtIJ;
                    Dp[6*PIT + o + 3]  = -dt*ctskIJ + hdt2*(ctwIJ + wctIJ);
                    Dp[6*PIT + o + 9]  = EmTIJ - dij;
                    Dp[6*PIT + o + 12] = -dt*vskIJ + hdt2*(ctskIJ + wvIJ);
                    Dp[6*PIT + o + 15] = -dt*dij + hdt2*wskIJ;
                }
            }
            if (t==3) S.dts[s] = dt;
            // wave0: D(s) -> Ws(s) = W * sqrt(Rd)  (intra-wave sync only)
            if (w==0){
                __builtin_amdgcn_wave_barrier();
                asm volatile("s_waitcnt lgkmcnt(0)" ::: "memory");
                __builtin_amdgcn_wave_barrier();
                float* Wp = S.Wsall[s];
                const float* Dp2 = S.Dall[s];
                for (int e=l;e<108;e+=64){
                    int i=e/12, j=e%12;
                    const float* Dr = &Dp2[i*PIT];
                    int ri = 3+i;
                    float val;
                    if (j<3){
                        float v0j = sel3(j, 0.f, -vv2,  vv1);
                        float v1j = sel3(j, vv2,  0.f, -vv0);
                        float v2j = sel3(j,-vv1,  vv0,  0.f);
                        val = -((ri==3+j)?1.f:0.f) - Dr[3+j]
                              - (((ri==9 )?1.f:0.f)+Dr[9 ])*v0j
                              - (((ri==10)?1.f:0.f)+Dr[10])*v1j
                              - (((ri==11)?1.f:0.f)+Dr[11])*v2j;
                    } else if (j<6) val = Dr[9+j];
                    else if (j<9) val = -(((ri==j+3)?1.f:0.f) + Dr[j+3]);
                    else val = Dr[6+j];
                    Wp[i*12+j] = val * S.sqRd[j];
                }
            }

            // accumulators (all lanes, pre-update values)
            float d2 = dt*dt;
            float e0=d2*a0, e1=d2*a1, e2=d2*a2;
            ra0 += va0*dt + 0.5f*(Cc[0]*e0+Cc[1]*e1+Cc[2]*e2);
            ra1 += va1*dt + 0.5f*(Cc[3]*e0+Cc[4]*e1+Cc[5]*e2);
            ra2 += va2*dt + 0.5f*(Cc[6]*e0+Cc[7]*e1+Cc[8]*e2);
            float da0=dt*a0, da1=dt*a1, da2=dt*a2;
            va0 += Cc[0]*da0+Cc[1]*da1+Cc[2]*da2;
            va1 += Cc[3]*da0+Cc[4]*da1+Cc[5]*da2;
            va2 += Cc[6]*da0+Cc[7]*da1+Cc[8]*da2;
            float Cn[9]; mm3(Cc, Em, Cn);
#pragma unroll
            for (int q=0;q<9;q++) Cc[q]=Cn[q];
            tac += dt;
        }
        __syncthreads();

        // =========== PREDICT: covariance chain (ONE block barrier/substep) ===========
        for (int s=0;s<NIM-1;s++){
            float* Pc = (s&1) ? S.P1 : S.P0;
            float* Pn = (s&1) ? S.P0 : S.P1;
            const float* Ds = S.Dall[s];
            const float* Wss = S.Wsall[s];
            float dt = S.dts[s];

            // phase b': A rows (wave-split), D-row sparse
            //   D rows 0..2: cols {3..5,12..14}; rows 3..5: {0..5,9..11,15..17}; rows 6..8: +{12..14}
            int aBeg = (w==0)?0:57, aEnd = (w==0)?57:171;
            for (int e=aBeg+l;e<aEnd;e+=64){
                int i=e/19, j=e%19;
                const float* Dr = &Ds[i*PIT];
                float s2 = Pc[(3+i)*PIT+j]
                         + Dr[3]*Pc[3*PIT+j]+Dr[4]*Pc[4*PIT+j]+Dr[5]*Pc[5*PIT+j];
                if (i<3){
                    s2 += Dr[12]*Pc[12*PIT+j]+Dr[13]*Pc[13*PIT+j]+Dr[14]*Pc[14*PIT+j];
                } else {
                    s2 += Dr[0]*Pc[0*PIT+j]+Dr[1]*Pc[1*PIT+j]+Dr[2]*Pc[2*PIT+j]
                        + Dr[9]*Pc[9*PIT+j]+Dr[10]*Pc[10*PIT+j]+Dr[11]*Pc[11*PIT+j]
                        + Dr[15]*Pc[15*PIT+j]+Dr[16]*Pc[16*PIT+j]+Dr[17]*Pc[17*PIT+j];
                    if (i>=6) s2 += Dr[12]*Pc[12*PIT+j]+Dr[13]*Pc[13*PIT+j]+Dr[14]*Pc[14*PIT+j];
                }
                S.A9[i*PIT+j]=s2;
            }
            __builtin_amdgcn_wave_barrier();
            asm volatile("s_waitcnt lgkmcnt(0)" ::: "memory");
            __builtin_amdgcn_wave_barrier();

            // phase c: tri (wave-split by row ownership; sparse D-dot)
            int tBase = (w==0)?0:99, tCnt = (w==0)?99:91;
            for (int e2=l;e2<tCnt;e2+=64){
                int tt=S.tri[tBase+e2]; int i=tt>>5, j=tt&31;
                const float* Ai = (i>=3 && i<12) ? &S.A9[(i-3)*PIT] : &Pc[i*PIT];
                float val = Ai[j];
                if (j>=3 && j<12) val += dotD(Ai, &Ds[(j-3)*PIT], (j-3)/3);
                if (i>=3){
                    if (j<12) val += dt*dot12_rr(&Wss[(i-3)*12], &Wss[(j-3)*12]);
                    else if (i<12){
                        if (j<15) val += dt*Wss[(i-3)*12 + (j-9)]*S.sqRd[j-9];
                        else if (j<18) val += dt*Wss[(i-3)*12 + (j-6)]*S.sqRd[j-6];
                    } else if (i==j){
                        if (i<15) val += dt*S.Rd[i-9];
                        else if (i<18) val += dt*S.Rd[i-6];
                    }
                }
                Pn[i*PIT+j]=val; Pn[j*PIT+i]=val;
            }
            __syncthreads();
        }
        // NIM-1 = 10 even -> covariance in P0

        // pred_state (uniform per filter)
        float t2a = tac*tac;
        float rp0 = vk0*tac - 0.5f*g0*t2a + ra0;
        float rp1 = vk1*tac - 0.5f*g1*t2a + ra1;
        float rp2 = vk2*tac - 0.5f*g2*t2a + ra2;
        float u0=vk0-g0*tac+va0, u1=vk1-g1*tac+va1, u2=vk2-g2*tac+va2;
        float vpr0=Cc[0]*u0+Cc[3]*u1+Cc[6]*u2;
        float vpr1=Cc[1]*u0+Cc[4]*u1+Cc[7]*u2;
        float vpr2=Cc[2]*u0+Cc[5]*u1+Cc[8]*u2;

        // =========== UPDATE (R12 structure) ===========
        float phi[3]; log_SO3(Cc, phi);
        float nphi[3]={-phi[0],-phi[1],-phi[2]};
        float Jli[9]; J_left_inv(nphi, Jli);
        const float* vm = vis_meas + ((size_t)b*NT+k)*6;
        float res0=vm[0]-phi[0], res1=vm[1]-phi[1], res2=vm[2]-phi[2];
        float res3=vm[3]-lam*rp0, res4=vm[4]-lam*rp1, res5=vm[5]-lam*rp2;

        // PHt -> Wu cols 0..5 (register selects)
        if (t<114){
            int i=t/6, j=t%6;
            float val;
            if (j<3){
                float jr0 = sel3(j, Jli[0], Jli[3], Jli[6]);
                float jr1 = sel3(j, Jli[1], Jli[4], Jli[7]);
                float jr2 = sel3(j, Jli[2], Jli[5], Jli[8]);
                val = S.P0[i*PIT+3]*jr0 + S.P0[i*PIT+4]*jr1 + S.P0[i*PIT+5]*jr2;
            } else {
                float rsel = sel3(j-3, rp0, rp1, rp2);
                val = lam*S.P0[i*PIT+6+(j-3)] + rsel*S.P0[i*PIT+18];
            }
            S.Wu[i*12+j]=val;
        }
        __syncthreads();
        // Aug[0] = [S | I]
        const float* vmc = vis_covar + ((size_t)b*NT+k)*36;
        if (t<84){
            int i=t/14, c=t%14;
            float val;
            if (c<6){
                float hp;
                if (i<3){
                    float jr0 = sel3(i, Jli[0], Jli[3], Jli[6]);
                    float jr1 = sel3(i, Jli[1], Jli[4], Jli[7]);
                    float jr2 = sel3(i, Jli[2], Jli[5], Jli[8]);
                    hp = jr0*S.Wu[3*12+c]+jr1*S.Wu[4*12+c]+jr2*S.Wu[5*12+c];
                } else {
                    float rsel = sel3(i-3, rp0, rp1, rp2);
                    hp = lam*S.Wu[(3+i)*12+c] + rsel*S.Wu[18*12+c];
                }
                val = hp + vmc[i*6+c];
            } else val = ((c-6)==i)?1.f:0.f;
            S.Aug[0][i*14+c]=val;
        }
        __syncthreads();
        // Gauss-Jordan: wave 0, lockstep ping-pong
        if (t<64){
            int i0=t/14, c0=t%14;
            int e1=t+64, i1=e1/14, c1=e1%14;
            bool h1 = e1<84;
            int cur=0;
#pragma unroll
            for (int kk=0;kk<6;kk++){
                const float* Ac = S.Aug[cur];
                float* An = S.Aug[cur^1];
                float rpv = 1.0f/Ac[kk*14+kk];
                float piv0 = Ac[kk*14+c0]*rpv;
                float nv0 = (i0==kk)? piv0 : (Ac[i0*14+c0] - Ac[i0*14+kk]*piv0);
                float nv1 = 0.f;
                if (h1){
                    float piv1 = Ac[kk*14+c1]*rpv;
                    nv1 = (i1==kk)? piv1 : (Ac[i1*14+c1] - Ac[i1*14+kk]*piv1);
                }
                An[i0*14+c0]=nv0;
                if (h1) An[i1*14+c1]=nv1;
                cur^=1;
                __builtin_amdgcn_wave_barrier();
            }
        }
        __syncthreads();
        // K = PHt @ Sinv -> Mu   (Sinv in Aug[0] cols 6..13)
        if (t<114){
            int i=t/6, j=t%6;
            float s2=0.f;
#pragma unroll
            for (int m=0;m<6;m++) s2 += S.Wu[i*12+m]*S.Aug[0][m*14+6+j];
            S.Mu[i*12+j]=s2;
        }
        __syncthreads();
        // KH compact (cols {3..8,18}) -> Wu cols 0..6 ; E = K @ residual
        for (int e=t;e<133;e+=NTH){
            int i=e/7, c=e%7;
            float val;
            if (c<3){
                float jc0 = sel3(c, Jli[0], Jli[1], Jli[2]);
                float jc1 = sel3(c, Jli[3], Jli[4], Jli[5]);
                float jc2 = sel3(c, Jli[6], Jli[7], Jli[8]);
                val = S.Mu[i*12+0]*jc0 + S.Mu[i*12+1]*jc1 + S.Mu[i*12+2]*jc2;
            }
            else if (c<6) val = S.Mu[i*12+c]*lam;
            else val = S.Mu[i*12+3]*rp0 + S.Mu[i*12+4]*rp1 + S.Mu[i*12+5]*rp2;
            S.Wu[i*12+c]=val;
        }
        if (t<19){
            S.E[t] = S.Mu[t*12+0]*res0 + S.Mu[t*12+1]*res1 + S.Mu[t*12+2]*res2
                   + S.Mu[t*12+3]*res3 + S.Mu[t*12+4]*res4 + S.Mu[t*12+5]*res5;
        }
        __syncthreads();
        // estP = (I - KH) P0 -> P1  ; + uniform est_state/composition math
        for (int e=t;e<361;e+=NTH){
            int i=e/19, j=e%19;
            float s2 = S.P0[i*PIT+j];
#pragma unroll
            for (int c=0;c<6;c++) s2 -= S.Wu[i*12+c]*S.P0[(3+c)*PIT+j];
            s2 -= S.Wu[i*12+6]*S.P0[18*PIT+j];
            S.P1[i*PIT+j]=s2;
        }
        float ev[19];
#pragma unroll
        for (int q=0;q<19;q++) ev[q]=S.E[q];
        g0+=ev[0]; g1+=ev[1]; g2+=ev[2];
        float dE[9]; exp_SO3f(ev[3], ev[4], ev[5], dE);
        float Ce[9]; mm3(Cc,dE,Ce);
        float re0=rp0+ev[6], re1=rp1+ev[7], re2=rp2+ev[8];
        float vE0=vpr0+ev[9], vE1=vpr1+ev[10], vE2=vpr2+ev[11];
        bw0+=ev[12]; bw1+=ev[13]; bw2+=ev[14];
        ba0+=ev[15]; ba1+=ev[16]; ba2+=ev[17];
        lam+=ev[18];
        float gn0=Ce[0]*g0+Ce[3]*g1+Ce[6]*g2;
        float gn1=Ce[1]*g0+Ce[4]*g1+Ce[7]*g2;
        float gn2=Ce[2]*g0+Ce[5]*g1+Ce[8]*g2;
        float Rn[9];
#pragma unroll
        for (int i=0;i<3;i++)
#pragma unroll
            for (int j=0;j<3;j++)
                Rn[i*3+j] = Ce[0*3+i]*pR[0*3+j] + Ce[1*3+i]*pR[1*3+j] + Ce[2*3+i]*pR[2*3+j];
        float dv0=pT0-re0, dv1=pT1-re1, dv2=pT2-re2;
        float Tn0=Ce[0]*dv0+Ce[3]*dv1+Ce[6]*dv2;
        float Tn1=Ce[1]*dv0+Ce[4]*dv1+Ce[7]*dv2;
        float Tn2=Ce[2]*dv0+Ce[5]*dv1+Ce[8]*dv2;
        __syncthreads();
        // new_covar = sym(U estP U^T) computed DIRECTLY from P1 (T-phase fused)
        size_t obase = (size_t)b*17 + (size_t)(k+1);
        for (int e=t;e<190;e+=NTH){
            int tt=S.tri[e]; int i=tt>>5, j=tt&31;
            float val;
            if (i<3){
                float ui0 = sel3(i, Ce[0], Ce[1], Ce[2]);
                float ui1 = sel3(i, Ce[3], Ce[4], Ce[5]);
                float ui2 = sel3(i, Ce[6], Ce[7], Ce[8]);
                float ui3 = sel3(i, 0.f,  gn2, -gn1);
                float ui4 = sel3(i, -gn2, 0.f,  gn0);
                float ui5 = sel3(i, gn1, -gn0,  0.f);
                if (j>=3){
                    val = ui0*S.P1[0*PIT+j] + ui1*S.P1[1*PIT+j] + ui2*S.P1[2*PIT+j]
                        + ui3*S.P1[3*PIT+j] + ui4*S.P1[4*PIT+j] + ui5*S.P1[5*PIT+j];
                } else {
                    float uj0 = sel3(j, Ce[0], Ce[1], Ce[2]);
                    float uj1 = sel3(j, Ce[3], Ce[4], Ce[5]);
                    float uj2 = sel3(j, Ce[6], Ce[7], Ce[8]);
                    float uj3 = sel3(j, 0.f,  gn2, -gn1);
                    float uj4 = sel3(j, -gn2, 0.f,  gn0);
                    float uj5 = sel3(j, gn1, -gn0,  0.f);
                    val = 0.f;
#pragma unroll
                    for (int n=0;n<6;n++){
                        float un = (n==0)?uj0:(n==1)?uj1:(n==2)?uj2:(n==3)?uj3:(n==4)?uj4:uj5;
                        float tn = ui0*S.P1[0*PIT+n] + ui1*S.P1[1*PIT+n] + ui2*S.P1[2*PIT+n]
                                 + ui3*S.P1[3*PIT+n] + ui4*S.P1[4*PIT+n] + ui5*S.P1[5*PIT+n];
                        val += un*tn;
                    }
                }
            } else {
                val = S.P1[i*PIT+j];
            }
            bool msk = (i>=3&&i<9)||(j>=3&&j<9);
            float pv = msk ? 0.f : val;
            S.P0[i*PIT+j]=pv; S.P0[j*PIT+i]=pv;
            out_covars[obase*361 + i*19 + j] = val;
            if (i!=j) out_covars[obase*361 + j*19 + i] = val;
        }
        if (t==0){
            float* po = out_poses + obase*16;
            po[0]=Rn[0]; po[1]=Rn[1]; po[2]=Rn[2];  po[3]=Tn0;
            po[4]=Rn[3]; po[5]=Rn[4]; po[6]=Rn[5];  po[7]=Tn1;
            po[8]=Rn[6]; po[9]=Rn[7]; po[10]=Rn[8]; po[11]=Tn2;
            po[12]=0.f; po[13]=0.f; po[14]=0.f; po[15]=1.f;
            float* so = out_states + obase*25;
            so[0]=gn0; so[1]=gn1; so[2]=gn2;
#pragma unroll
            for (int q=0;q<9;q++) so[3+q]=Ce[q];
            so[12]=re0; so[13]=re1; so[14]=re2;
            so[15]=vE0; so[16]=vE1; so[17]=vE2;
            so[18]=bw0; so[19]=bw1; so[20]=bw2;
            so[21]=ba0; so[22]=ba1; so[23]=ba2;
            so[24]=lam;
        }
        // carry
        g0=gn0; g1=gn1; g2=gn2;
        vk0=vE0; vk1=vE1; vk2=vE2;
#pragma unroll
        for (int q=0;q<9;q++) pR[q]=Rn[q];
        pT0=Tn0; pT1=Tn1; pT2=Tn2;
        __syncthreads();
    }
}

extern "C" void kernel_launch(void* const* d_in, const int* in_sizes, int n_in,
                              void* d_out, int out_size, void* d_ws, size_t ws_size,
                              hipStream_t stream) {
    const float* imu    = (const float*)d_in[0];
    const float* Rimu   = (const float*)d_in[1];
    const float* ppose  = (const float*)d_in[2];
    const float* pstate = (const float*)d_in[3];
    const float* pcov   = (const float*)d_in[4];
    const float* vm     = (const float*)d_in[5];
    const float* vmc    = (const float*)d_in[6];
    float* out = (float*)d_out;
    float* out_poses  = out;
    float* out_states = out + (size_t)NB*17*16;
    float* out_covars = out + (size_t)NB*17*16 + (size_t)NB*17*25;
    hipLaunchKernelGGL(kf_kernel, dim3(NB), dim3(NTH), 0, stream,
        imu, Rimu, ppose, pstate, pcov, vm, vmc, out_poses, out_states, out_covars);
}

// Round 17
// 611.817 us; speedup vs baseline: 1.0460x; 1.0460x over previous
//
#include <hip/hip_runtime.h>

#define NB 1024
#define NT 16
#define NIM 11
#define PIT 20
#define NTH 128   // one filter per 128-thread block

struct __align__(16) SharedBlob {
    float P0[19*PIT];
    float P1[19*PIT];
    float A9[9*PIT];        // A = (Phi P) rows 3..11
    float Dall[10][9*PIT];  // Delta rows 3..11 per substep (static zeros elsewhere)
    float Wsall[10][9*12];  // W * sqrt(Rd) per substep
    float Wu[19*12];        // PHt (cols 0..5) then KH (cols 0..6)
    float Mu[19*12];        // K
    float T[3*PIT];
    float Rd[12];
    float sqRd[12];
    float Aug[2][84];
    float E[20];
    float dts[12];          // dt per substep
    unsigned short tri[192];
};

__device__ __forceinline__ float sel3(int i, float a, float b, float c){
    return i==0 ? a : (i==1 ? b : c);
}
__device__ __forceinline__ void skew3(float x, float y, float z, float K[9]) {
    K[0]=0.f;  K[1]=-z;   K[2]=y;
    K[3]=z;    K[4]=0.f;  K[5]=-x;
    K[6]=-y;   K[7]=x;    K[8]=0.f;
}
__device__ __forceinline__ void mm3(const float A[9], const float Bm[9], float C[9]) {
#pragma unroll
    for (int i=0;i<3;i++)
#pragma unroll
        for (int j=0;j<3;j++)
            C[i*3+j] = A[i*3+0]*Bm[0+j] + A[i*3+1]*Bm[3+j] + A[i*3+2]*Bm[6+j];
}
__device__ __forceinline__ void exp_SO3f(float p0, float p1, float p2, float R[9]) {
    float t2 = p0*p0+p1*p1+p2*p2;
    bool sm = t2 < 1e-8f;
    float t2s = sm ? 1.0f : t2;
    float t = sqrtf(t2s);
    float sn, cs; __sincosf(t, &sn, &cs);
    float A = sm ? (1.0f - t2*(1.0f/6.0f)) : (sn/t);
    float Bc = sm ? (0.5f - t2*(1.0f/24.0f)) : ((1.0f - cs)/t2s);
    float K[9]; skew3(p0,p1,p2,K);
    float K2[9]; mm3(K,K,K2);
#pragma unroll
    for (int i=0;i<9;i++) R[i] = A*K[i] + Bc*K2[i];
    R[0]+=1.f; R[4]+=1.f; R[8]+=1.f;
}
__device__ __forceinline__ void log_SO3(const float C[9], float p[3]) {
    float tr = C[0]+C[4]+C[8];
    float c = (tr-1.0f)*0.5f;
    c = fminf(fmaxf(c, -1.0f+1e-7f), 1.0f-1e-7f);
    float t = acosf(c);
    bool sm = t < 1e-4f;
    float s = sm ? 1.0f : sinf(t);
    float coef = sm ? (0.5f + t*t*(1.0f/12.0f)) : (t/(2.0f*s));
    p[0] = coef*(C[7]-C[5]);
    p[1] = coef*(C[2]-C[6]);
    p[2] = coef*(C[3]-C[1]);
}
__device__ __forceinline__ void J_left_inv(const float p[3], float J[9]) {
    float t2 = p[0]*p[0]+p[1]*p[1]+p[2]*p[2];
    bool sm = t2 < 1e-8f;
    float t2s = sm ? 1.0f : t2;
    float t = sqrtf(t2s);
    float coef = sm ? (1.0f/12.0f) : (1.0f/t2s - (1.0f+cosf(t))/(2.0f*t*sinf(t)));
    float K[9]; skew3(p[0],p[1],p[2],K);
    float K2[9]; mm3(K,K,K2);
#pragma unroll
    for (int i=0;i<9;i++) J[i] = -0.5f*K[i] + coef*K2[i];
    J[0]+=1.f; J[4]+=1.f; J[8]+=1.f;
}
__device__ __forceinline__ float dot12_rr(const float* a, const float* b){
    const float4* a4=(const float4*)a;
    const float4* b4=(const float4*)b;
    float s=0.f;
#pragma unroll
    for (int q=0;q<3;q++){
        float4 x=a4[q], y=b4[q];
        s += x.x*y.x + x.y*y.y + x.z*y.z + x.w*y.w;
    }
    return s;
}
// D-row sparse dot: jb = (row block of D), exploits static zero pattern
__device__ __forceinline__ float dotD(const float* Ai, const float* Dr, int jb){
    float s = Ai[3]*Dr[3]+Ai[4]*Dr[4]+Ai[5]*Dr[5];
    if (jb==0){
        s += Ai[12]*Dr[12]+Ai[13]*Dr[13]+Ai[14]*Dr[14];
    } else {
        s += Ai[0]*Dr[0]+Ai[1]*Dr[1]+Ai[2]*Dr[2]
           + Ai[9]*Dr[9]+Ai[10]*Dr[10]+Ai[11]*Dr[11]
           + Ai[15]*Dr[15]+Ai[16]*Dr[16]+Ai[17]*Dr[17];
        if (jb==2) s += Ai[12]*Dr[12]+Ai[13]*Dr[13]+Ai[14]*Dr[14];
    }
    return s;
}

__global__ void __launch_bounds__(NTH, 2) kf_kernel(
    const float* __restrict__ imu_data,
    const float* __restrict__ Rimu,
    const float* __restrict__ prev_pose,
    const float* __restrict__ prev_state,
    const float* __restrict__ prev_covar,
    const float* __restrict__ vis_meas,
    const float* __restrict__ vis_covar,
    float* __restrict__ out_poses,
    float* __restrict__ out_states,
    float* __restrict__ out_covars)
{
    __shared__ SharedBlob S;
    const int t = threadIdx.x;         // thread within filter
    const int b = blockIdx.x;          // batch element
    const int w = t >> 6;              // wave (0/1)
    const int l = t & 63;              // lane within wave

    // ---- init ----
    const float* pcv = prev_covar + (size_t)b*361;
    for (int e=t;e<361;e+=NTH){
        float v = pcv[e];
        int i=e/19, j=e%19;
        bool msk = (i>=3&&i<9)||(j>=3&&j<9);
        S.P0[i*PIT + j] = msk ? 0.f : v;      // masked for first predict
        out_covars[((size_t)b*17)*361 + e] = v;
    }
    for (int e=t;e<10*9*PIT;e+=NTH) S.Dall[0][e] = 0.f;   // static zero pattern
    if (t<12){ float rv = Rimu[t*12+t]; S.Rd[t]=rv; S.sqRd[t]=sqrtf(rv); }
    if (t<16) out_poses[((size_t)b*17)*16 + t] = prev_pose[(size_t)b*16+t];
    if (t<25) out_states[((size_t)b*17)*25 + t] = prev_state[(size_t)b*25+t];
    for (int e=t;e<190;e+=NTH){
        int i=0, rem=e;
        while (rem >= 19-i){ rem -= 19-i; i++; }
        S.tri[e] = (unsigned short)((i<<5)|(i+rem));
    }

    const float* st = prev_state + (size_t)b*25;
    float g0=st[0], g1=st[1], g2=st[2];
    float vk0=st[15], vk1=st[16], vk2=st[17];
    float bw0=st[18], bw1=st[19], bw2=st[20];
    float ba0=st[21], ba1=st[22], ba2=st[23];
    float lam=st[24];
    const float* pp = prev_pose + (size_t)b*16;
    float pR[9] = {pp[0],pp[1],pp[2], pp[4],pp[5],pp[6], pp[8],pp[9],pp[10]};
    float pT0=pp[3], pT1=pp[7], pT2=pp[11];

    __syncthreads();

    for (int k=0;k<NT;k++){
        // =========== PREDICT: precompute phase (no block barriers) ===========
        float Cc[9] = {1,0,0, 0,1,0, 0,0,1};
        float ra0=0,ra1=0,ra2=0, va0=0,va1=0,va2=0, tac=0;
        const float* imu = imu_data + ((size_t)b*NT + k)*NIM*7;

        for (int s=0;s<NIM-1;s++){
            const float* m0 = imu + s*7;
            float dt = m0[7] - m0[0];
            float w0=m0[1]-bw0, w1=m0[2]-bw1, w2=m0[3]-bw2;
            float a0=m0[4]-ba0, a1=m0[5]-ba1, a2=m0[6]-ba2;
            float u0=vk0-g0*tac+va0, u1=vk1-g1*tac+va1, u2=vk2-g2*tac+va2;
            float vv0=Cc[0]*u0+Cc[3]*u1+Cc[6]*u2;
            float vv1=Cc[1]*u0+Cc[4]*u1+Cc[7]*u2;
            float vv2=Cc[2]*u0+Cc[5]*u1+Cc[8]*u2;
            float ct0=Cc[0]*g0+Cc[3]*g1+Cc[6]*g2;
            float ct1=Cc[1]*g0+Cc[4]*g1+Cc[7]*g2;
            float ct2=Cc[2]*g0+Cc[5]*g1+Cc[8]*g2;
            float Em[9]; exp_SO3f(dt*w0, dt*w1, dt*w2, Em);
            float hdt2 = 0.5f*dt*dt;

            // wave0 lanes 0..26 write Delta(s) entries (disjoint per-substep buffers)
            if (t<27){
                int r=t/9, ii=(t%9)/3, jj=t%3;
                float dij = (ii==jj)?1.f:0.f;
                int o = ii*PIT + jj;
                float* Dp = S.Dall[s];
                if (r==0){
                    float eJ0=sel3(jj,Em[0],Em[3],Em[6]), eJ1=sel3(jj,Em[1],Em[4],Em[7]), eJ2=sel3(jj,Em[2],Em[5],Em[8]);
                    float EmTIJ = sel3(ii,eJ0,eJ1,eJ2);
                    float wcJ0=sel3(jj,0.f,-w2,w1), wcJ1=sel3(jj,w2,0.f,-w0), wcJ2=sel3(jj,-w1,w0,0.f);
                    float wskIJ = sel3(ii,wcJ0,wcJ1,wcJ2);
                    Dp[o+3]  = EmTIJ - dij;
                    Dp[o+12] = -dt*dij + hdt2*wskIJ;
                } else if (r==1){
                    float cI0=sel3(ii,Cc[0],Cc[3],Cc[6]), cI1=sel3(ii,Cc[1],Cc[4],Cc[7]), cI2=sel3(ii,Cc[2],Cc[5],Cc[8]);
                    float cJ0=sel3(jj,Cc[0],Cc[3],Cc[6]), cJ1=sel3(jj,Cc[1],Cc[4],Cc[7]), cJ2=sel3(jj,Cc[2],Cc[5],Cc[8]);
                    float ccJ0=sel3(jj,Cc[0],Cc[1],Cc[2]), ccJ1=sel3(jj,Cc[3],Cc[4],Cc[5]), ccJ2=sel3(jj,Cc[6],Cc[7],Cc[8]);
                    float CIJ = sel3(ii,ccJ0,ccJ1,ccJ2);
                    float vcJ0=sel3(jj,0.f,-vv2,vv1), vcJ1=sel3(jj,vv2,0.f,-vv0), vcJ2=sel3(jj,-vv1,vv0,0.f);
                    float tcJ0=sel3(jj,0.f,-ct2,ct1), tcJ1=sel3(jj,ct2,0.f,-ct0), tcJ2=sel3(jj,-ct1,ct0,0.f);
                    float wcJ0=sel3(jj,0.f,-w2,w1), wcJ1=sel3(jj,w2,0.f,-w0), wcJ2=sel3(jj,-w1,w0,0.f);
                    float CCtIJ  = cI0*cJ0 + cI1*cJ1 + cI2*cJ2;
                    float CvskIJ = cI0*vcJ0 + cI1*vcJ1 + cI2*vcJ2;
                    float Cv0 =  cI1*vv2 - cI2*vv1;
                    float Cv1 = -cI0*vv2 + cI2*vv0;
                    float Cv2 =  cI0*vv1 - cI1*vv0;
                    float CvwIJ = Cv0*wcJ0 + Cv1*wcJ1 + Cv2*wcJ2;
                    float CctIJ = cI0*tcJ0 + cI1*tcJ1 + cI2*tcJ2;
                    float CwIJ  = cI0*wcJ0 + cI1*wcJ1 + cI2*wcJ2;
                    Dp[3*PIT + o + 0]  = -hdt2*CCtIJ;
                    Dp[3*PIT + o + 3]  = -dt*CvskIJ + hdt2*(CvwIJ - CctIJ);
                    Dp[3*PIT + o + 9]  =  dt*CIJ - hdt2*CwIJ;
                    Dp[3*PIT + o + 15] = -hdt2*CIJ;
                } else {
                    float cJ0=sel3(jj,Cc[0],Cc[3],Cc[6]), cJ1=sel3(jj,Cc[1],Cc[4],Cc[7]), cJ2=sel3(jj,Cc[2],Cc[5],Cc[8]);
                    float CTIJ = sel3(ii,cJ0,cJ1,cJ2);
                    float eJ0=sel3(jj,Em[0],Em[3],Em[6]), eJ1=sel3(jj,Em[1],Em[4],Em[7]), eJ2=sel3(jj,Em[2],Em[5],Em[8]);
                    float EmTIJ = sel3(ii,eJ0,eJ1,eJ2);
                    float wrI0=sel3(ii,0.f,w2,-w1), wrI1=sel3(ii,-w2,0.f,w0), wrI2=sel3(ii,w1,-w0,0.f);
                    float wcJ0=sel3(jj,0.f,-w2,w1), wcJ1=sel3(jj,w2,0.f,-w0), wcJ2=sel3(jj,-w1,w0,0.f);
                    float wskIJ = sel3(ii,wcJ0,wcJ1,wcJ2);
                    float vcJ0=sel3(jj,0.f,-vv2,vv1), vcJ1=sel3(jj,vv2,0.f,-vv0), vcJ2=sel3(jj,-vv1,vv0,0.f);
                    float vskIJ = sel3(ii,vcJ0,vcJ1,vcJ2);
                    float trI0=sel3(ii,0.f,ct2,-ct1), trI1=sel3(ii,-ct2,0.f,ct0), trI2=sel3(ii,ct1,-ct0,0.f);
                    float tcJ0=sel3(jj,0.f,-ct2,ct1), tcJ1=sel3(jj,ct2,0.f,-ct0), tcJ2=sel3(jj,-ct1,ct0,0.f);
                    float ctskIJ = sel3(ii,tcJ0,tcJ1,tcJ2);
                    float wCtIJ = wrI0*cJ0 + wrI1*cJ1 + wrI2*cJ2;
                    float ctwIJ = trI0*wcJ0 + trI1*wcJ1 + trI2*wcJ2;
                    float wctIJ = wrI0*tcJ0 + wrI1*tcJ1 + wrI2*tcJ2;
                    float wvIJ  = wrI0*vcJ0 + wrI1*vcJ1 + wrI2*vcJ2;
                    Dp[6*PIT + o + 0]  = -dt*CTIJ + hdt2*wCtIJ;
                    Dp[6*PIT + o + 3]  = -dt*ctskIJ + hdt2*(ctwIJ + wctIJ);
                    Dp[6*PIT + o + 9]  = EmTIJ - dij;
                    Dp[6*PIT + o + 12] = -dt*vskIJ + hdt2*(ctskIJ + wvIJ);
                    Dp[6*PIT + o + 15] = -dt*dij + hdt2*wskIJ;
                }
            }
            if (t==3) S.dts[s] = dt;
            // wave0: D(s) -> Ws(s) = W * sqrt(Rd)  (intra-wave sync only)
            if (w==0){
                __builtin_amdgcn_wave_barrier();
                asm volatile("s_waitcnt lgkmcnt(0)" ::: "memory");
                __builtin_amdgcn_wave_barrier();
                float* Wp = S.Wsall[s];
                const float* Dp2 = S.Dall[s];
                for (int e=l;e<108;e+=64){
                    int i=e/12, j=e%12;
                    const float* Dr = &Dp2[i*PIT];
                    int ri = 3+i;
                    float val;
                    if (j<3){
                        float v0j = sel3(j, 0.f, -vv2,  vv1);
                        float v1j = sel3(j, vv2,  0.f, -vv0);
                        float v2j = sel3(j,-vv1,  vv0,  0.f);
                        val = -((ri==3+j)?1.f:0.f) - Dr[3+j]
                              - (((ri==9 )?1.f:0.f)+Dr[9 ])*v0j
                              - (((ri==10)?1.f:0.f)+Dr[10])*v1j
                              - (((ri==11)?1.f:0.f)+Dr[11])*v2j;
                    } else if (j<6) val = Dr[9+j];
                    else if (j<9) val = -(((ri==j+3)?1.f:0.f) + Dr[j+3]);
                    else val = Dr[6+j];
                    Wp[i*12+j] = val * S.sqRd[j];
                }
            }

            // accumulators (all lanes, pre-update values)
            float d2 = dt*dt;
            float e0=d2*a0, e1=d2*a1, e2=d2*a2;
            ra0 += va0*dt + 0.5f*(Cc[0]*e0+Cc[1]*e1+Cc[2]*e2);
            ra1 += va1*dt + 0.5f*(Cc[3]*e0+Cc[4]*e1+Cc[5]*e2);
            ra2 += va2*dt + 0.5f*(Cc[6]*e0+Cc[7]*e1+Cc[8]*e2);
            float da0=dt*a0, da1=dt*a1, da2=dt*a2;
            va0 += Cc[0]*da0+Cc[1]*da1+Cc[2]*da2;
            va1 += Cc[3]*da0+Cc[4]*da1+Cc[5]*da2;
            va2 += Cc[6]*da0+Cc[7]*da1+Cc[8]*da2;
            float Cn[9]; mm3(Cc, Em, Cn);
#pragma unroll
            for (int q=0;q<9;q++) Cc[q]=Cn[q];
            tac += dt;
        }
        __syncthreads();

        // =========== PREDICT: covariance chain (ONE block barrier/substep) ===========
        for (int s=0;s<NIM-1;s++){
            float* Pc = (s&1) ? S.P1 : S.P0;
            float* Pn = (s&1) ? S.P0 : S.P1;
            const float* Ds = S.Dall[s];
            const float* Wss = S.Wsall[s];
            float dt = S.dts[s];

            // phase b': A rows (wave-split)
            int aBeg = (w==0)?0:57, aEnd = (w==0)?57:171;
            for (int e=aBeg+l;e<aEnd;e+=64){
                int i=e/19, j=e%19;
                const float* Dr = &Ds[i*PIT];
                float s2 = Pc[(3+i)*PIT+j]
                         + Dr[0]*Pc[0*PIT+j]+Dr[1]*Pc[1*PIT+j]+Dr[2]*Pc[2*PIT+j]
                         + Dr[3]*Pc[3*PIT+j]+Dr[4]*Pc[4*PIT+j]+Dr[5]*Pc[5*PIT+j]
                         + Dr[9]*Pc[9*PIT+j]+Dr[10]*Pc[10*PIT+j]+Dr[11]*Pc[11*PIT+j]
                         + Dr[12]*Pc[12*PIT+j]+Dr[13]*Pc[13*PIT+j]+Dr[14]*Pc[14*PIT+j]
                         + Dr[15]*Pc[15*PIT+j]+Dr[16]*Pc[16*PIT+j]+Dr[17]*Pc[17*PIT+j];
                S.A9[i*PIT+j]=s2;
            }
            __builtin_amdgcn_wave_barrier();
            asm volatile("s_waitcnt lgkmcnt(0)" ::: "memory");
            __builtin_amdgcn_wave_barrier();

            // phase c: tri (wave-split by row ownership; sparse D-dot)
            int tBase = (w==0)?0:99, tCnt = (w==0)?99:91;
            for (int e2=l;e2<tCnt;e2+=64){
                int tt=S.tri[tBase+e2]; int i=tt>>5, j=tt&31;
                const float* Ai = (i>=3 && i<12) ? &S.A9[(i-3)*PIT] : &Pc[i*PIT];
                float val = Ai[j];
                if (j>=3 && j<12) val += dotD(Ai, &Ds[(j-3)*PIT], (j-3)/3);
                if (i>=3){
                    if (j<12) val += dt*dot12_rr(&Wss[(i-3)*12], &Wss[(j-3)*12]);
                    else if (i<12){
                        if (j<15) val += dt*Wss[(i-3)*12 + (j-9)]*S.sqRd[j-9];
                        else if (j<18) val += dt*Wss[(i-3)*12 + (j-6)]*S.sqRd[j-6];
                    } else if (i==j){
                        if (i<15) val += dt*S.Rd[i-9];
                        else if (i<18) val += dt*S.Rd[i-6];
                    }
                }
                Pn[i*PIT+j]=val; Pn[j*PIT+i]=val;
            }
            __syncthreads();
        }
        // NIM-1 = 10 even -> covariance in P0

        // pred_state (uniform per filter)
        float t2a = tac*tac;
        float rp0 = vk0*tac - 0.5f*g0*t2a + ra0;
        float rp1 = vk1*tac - 0.5f*g1*t2a + ra1;
        float rp2 = vk2*tac - 0.5f*g2*t2a + ra2;
        float u0=vk0-g0*tac+va0, u1=vk1-g1*tac+va1, u2=vk2-g2*tac+va2;
        float vpr0=Cc[0]*u0+Cc[3]*u1+Cc[6]*u2;
        float vpr1=Cc[1]*u0+Cc[4]*u1+Cc[7]*u2;
        float vpr2=Cc[2]*u0+Cc[5]*u1+Cc[8]*u2;

        // =========== UPDATE (R9 structure) ===========
        float phi[3]; log_SO3(Cc, phi);
        float nphi[3]={-phi[0],-phi[1],-phi[2]};
        float Jli[9]; J_left_inv(nphi, Jli);
        const float* vm = vis_meas + ((size_t)b*NT+k)*6;
        float res0=vm[0]-phi[0], res1=vm[1]-phi[1], res2=vm[2]-phi[2];
        float res3=vm[3]-lam*rp0, res4=vm[4]-lam*rp1, res5=vm[5]-lam*rp2;

        // PHt -> Wu cols 0..5 (register selects)
        if (t<114){
            int i=t/6, j=t%6;
            float val;
            if (j<3){
                float jr0 = sel3(j, Jli[0], Jli[3], Jli[6]);
                float jr1 = sel3(j, Jli[1], Jli[4], Jli[7]);
                float jr2 = sel3(j, Jli[2], Jli[5], Jli[8]);
                val = S.P0[i*PIT+3]*jr0 + S.P0[i*PIT+4]*jr1 + S.P0[i*PIT+5]*jr2;
            } else {
                float rsel = sel3(j-3, rp0, rp1, rp2);
                val = lam*S.P0[i*PIT+6+(j-3)] + rsel*S.P0[i*PIT+18];
            }
            S.Wu[i*12+j]=val;
        }
        __syncthreads();
        // Aug[0] = [S | I]
        const float* vmc = vis_covar + ((size_t)b*NT+k)*36;
        if (t<84){
            int i=t/14, c=t%14;
            float val;
            if (c<6){
                float hp;
                if (i<3){
                    float jr0 = sel3(i, Jli[0], Jli[3], Jli[6]);
                    float jr1 = sel3(i, Jli[1], Jli[4], Jli[7]);
                    float jr2 = sel3(i, Jli[2], Jli[5], Jli[8]);
                    hp = jr0*S.Wu[3*12+c]+jr1*S.Wu[4*12+c]+jr2*S.Wu[5*12+c];
                } else {
                    float rsel = sel3(i-3, rp0, rp1, rp2);
                    hp = lam*S.Wu[(3+i)*12+c] + rsel*S.Wu[18*12+c];
                }
                val = hp + vmc[i*6+c];
            } else val = ((c-6)==i)?1.f:0.f;
            S.Aug[0][i*14+c]=val;
        }
        __syncthreads();
        // Gauss-Jordan: wave 0, lockstep ping-pong
        if (t<64){
            int i0=t/14, c0=t%14;
            int e1=t+64, i1=e1/14, c1=e1%14;
            bool h1 = e1<84;
            int cur=0;
#pragma unroll
            for (int kk=0;kk<6;kk++){
                const float* Ac = S.Aug[cur];
                float* An = S.Aug[cur^1];
                float rpv = 1.0f/Ac[kk*14+kk];
                float piv0 = Ac[kk*14+c0]*rpv;
                float nv0 = (i0==kk)? piv0 : (Ac[i0*14+c0] - Ac[i0*14+kk]*piv0);
                float nv1 = 0.f;
                if (h1){
                    float piv1 = Ac[kk*14+c1]*rpv;
                    nv1 = (i1==kk)? piv1 : (Ac[i1*14+c1] - Ac[i1*14+kk]*piv1);
                }
                An[i0*14+c0]=nv0;
                if (h1) An[i1*14+c1]=nv1;
                cur^=1;
                __builtin_amdgcn_wave_barrier();
            }
        }
        __syncthreads();
        // K = PHt @ Sinv -> Mu   (Sinv in Aug[0] cols 6..13)
        if (t<114){
            int i=t/6, j=t%6;
            float s2=0.f;
#pragma unroll
            for (int m=0;m<6;m++) s2 += S.Wu[i*12+m]*S.Aug[0][m*14+6+j];
            S.Mu[i*12+j]=s2;
        }
        __syncthreads();
        // KH compact (cols {3..8,18}) -> Wu cols 0..6 ; E = K @ residual
        for (int e=t;e<133;e+=NTH){
            int i=e/7, c=e%7;
            float val;
            if (c<3){
                float jc0 = sel3(c, Jli[0], Jli[1], Jli[2]);
                float jc1 = sel3(c, Jli[3], Jli[4], Jli[5]);
                float jc2 = sel3(c, Jli[6], Jli[7], Jli[8]);
                val = S.Mu[i*12+0]*jc0 + S.Mu[i*12+1]*jc1 + S.Mu[i*12+2]*jc2;
            }
            else if (c<6) val = S.Mu[i*12+c]*lam;
            else val = S.Mu[i*12+3]*rp0 + S.Mu[i*12+4]*rp1 + S.Mu[i*12+5]*rp2;
            S.Wu[i*12+c]=val;
        }
        if (t<19){
            S.E[t] = S.Mu[t*12+0]*res0 + S.Mu[t*12+1]*res1 + S.Mu[t*12+2]*res2
                   + S.Mu[t*12+3]*res3 + S.Mu[t*12+4]*res4 + S.Mu[t*12+5]*res5;
        }
        __syncthreads();
        // estP = (I - KH) P0 -> P1  ; + uniform est_state/composition math
        for (int e=t;e<361;e+=NTH){
            int i=e/19, j=e%19;
            float s2 = S.P0[i*PIT+j];
#pragma unroll
            for (int c=0;c<6;c++) s2 -= S.Wu[i*12+c]*S.P0[(3+c)*PIT+j];
            s2 -= S.Wu[i*12+6]*S.P0[18*PIT+j];
            S.P1[i*PIT+j]=s2;
        }
        float ev[19];
#pragma unroll
        for (int q=0;q<19;q++) ev[q]=S.E[q];
        g0+=ev[0]; g1+=ev[1]; g2+=ev[2];
        float dE[9]; exp_SO3f(ev[3], ev[4], ev[5], dE);
        float Ce[9]; mm3(Cc,dE,Ce);
        float re0=rp0+ev[6], re1=rp1+ev[7], re2=rp2+ev[8];
        float vE0=vpr0+ev[9], vE1=vpr1+ev[10], vE2=vpr2+ev[11];
        bw0+=ev[12]; bw1+=ev[13]; bw2+=ev[14];
        ba0+=ev[15]; ba1+=ev[16]; ba2+=ev[17];
        lam+=ev[18];
        float gn0=Ce[0]*g0+Ce[3]*g1+Ce[6]*g2;
        float gn1=Ce[1]*g0+Ce[4]*g1+Ce[7]*g2;
        float gn2=Ce[2]*g0+Ce[5]*g1+Ce[8]*g2;
        float Rn[9];
#pragma unroll
        for (int i=0;i<3;i++)
#pragma unroll
            for (int j=0;j<3;j++)
                Rn[i*3+j] = Ce[0*3+i]*pR[0*3+j] + Ce[1*3+i]*pR[1*3+j] + Ce[2*3+i]*pR[2*3+j];
        float dv0=pT0-re0, dv1=pT1-re1, dv2=pT2-re2;
        float Tn0=Ce[0]*dv0+Ce[3]*dv1+Ce[6]*dv2;
        float Tn1=Ce[1]*dv0+Ce[4]*dv1+Ce[7]*dv2;
        float Tn2=Ce[2]*dv0+Ce[5]*dv1+Ce[8]*dv2;
        __syncthreads();
        // T rows 0:3 = U @ estP  (register selects)
        if (t<57){
            int i=t/19, j=t%19;
            float c0 = sel3(i, Ce[0], Ce[1], Ce[2]);
            float c1 = sel3(i, Ce[3], Ce[4], Ce[5]);
            float c2 = sel3(i, Ce[6], Ce[7], Ce[8]);
            float gs0 = sel3(i, 0.f,  gn2, -gn1);
            float gs1 = sel3(i, -gn2, 0.f,  gn0);
            float gs2 = sel3(i, gn1, -gn0,  0.f);
            float val = c0*S.P1[0*PIT+j] + c1*S.P1[1*PIT+j] + c2*S.P1[2*PIT+j]
                      + gs0*S.P1[3*PIT+j] + gs1*S.P1[4*PIT+j] + gs2*S.P1[5*PIT+j];
            S.T[i*PIT+j]=val;
        }
        __syncthreads();
        // new_covar = sym((U estP) U^T): write P0 (masked for next predict) + out (raw)
        size_t obase = (size_t)b*17 + (size_t)(k+1);
        for (int e=t;e<190;e+=NTH){
            int tt=S.tri[e]; int i=tt>>5, j=tt&31;
            float val;
            if (j<3){ // then i<3
                float c0 = sel3(j, Ce[0], Ce[1], Ce[2]);
                float c1 = sel3(j, Ce[3], Ce[4], Ce[5]);
                float c2 = sel3(j, Ce[6], Ce[7], Ce[8]);
                float gs0 = sel3(j, 0.f,  gn2, -gn1);
                float gs1 = sel3(j, -gn2, 0.f,  gn0);
                float gs2 = sel3(j, gn1, -gn0,  0.f);
                val = S.T[i*PIT+0]*c0 + S.T[i*PIT+1]*c1 + S.T[i*PIT+2]*c2
                    + S.T[i*PIT+3]*gs0 + S.T[i*PIT+4]*gs1 + S.T[i*PIT+5]*gs2;
            } else {
                val = (i<3) ? S.T[i*PIT+j] : S.P1[i*PIT+j];
            }
            bool msk = (i>=3&&i<9)||(j>=3&&j<9);
            float pv = msk ? 0.f : val;
            S.P0[i*PIT+j]=pv; S.P0[j*PIT+i]=pv;
            out_covars[obase*361 + i*19 + j] = val;
            if (i!=j) out_covars[obase*361 + j*19 + i] = val;
        }
        if (t==0){
            float* po = out_poses + obase*16;
            po[0]=Rn[0]; po[1]=Rn[1]; po[2]=Rn[2];  po[3]=Tn0;
            po[4]=Rn[3]; po[5]=Rn[4]; po[6]=Rn[5];  po[7]=Tn1;
            po[8]=Rn[6]; po[9]=Rn[7]; po[10]=Rn[8]; po[11]=Tn2;
            po[12]=0.f; po[13]=0.f; po[14]=0.f; po[15]=1.f;
            float* so = out_states + obase*25;
            so[0]=gn0; so[1]=gn1; so[2]=gn2;
#pragma unroll
            for (int q=0;q<9;q++) so[3+q]=Ce[q];
            so[12]=re0; so[13]=re1; so[14]=re2;
            so[15]=vE0; so[16]=vE1; so[17]=vE2;
            so[18]=bw0; so[19]=bw1; so[20]=bw2;
            so[21]=ba0; so[22]=ba1; so[23]=ba2;
            so[24]=lam;
        }
        // carry
        g0=gn0; g1=gn1; g2=gn2;
        vk0=vE0; vk1=vE1; vk2=vE2;
#pragma unroll
        for (int q=0;q<9;q++) pR[q]=Rn[q];
        pT0=Tn0; pT1=Tn1; pT2=Tn2;
        __syncthreads();
    }
}

extern "C" void kernel_launch(void* const* d_in, const int* in_sizes, int n_in,
                              void* d_out, int out_size, void* d_ws, size_t ws_size,
                              hipStream_t stream) {
    const float* imu    = (const float*)d_in[0];
    const float* Rimu   = (const float*)d_in[1];
    const float* ppose  = (const float*)d_in[2];
    const float* pstate = (const float*)d_in[3];
    const float* pcov   = (const float*)d_in[4];
    const float* vm     = (const float*)d_in[5];
    const float* vmc    = (const float*)d_in[6];
    float* out = (float*)d_out;
    float* out_poses  = out;
    float* out_states = out + (size_t)NB*17*16;
    float* out_covars = out + (size_t)NB*17*16 + (size_t)NB*17*25;
    hipLaunchKernelGGL(kf_kernel, dim3(NB), dim3(NTH), 0, stream,
        imu, Rimu, ppose, pstate, pcov, vm, vmc, out_poses, out_states, out_covars);
}